// Round 3
// baseline (251.070 us; speedup 1.0000x reference)
//
#include <hip/hip_runtime.h>

// Problem constants (B,C,H,W = 32,64,128,128)
static constexpr int Cc  = 64;
static constexpr int HWc = 16384;   // 128*128
static constexpr int Bc  = 32;
static constexpr int TPX = 32;      // pixels per tile per wave
static constexpr int TT  = 4;       // tiles per wave

// ---------------------------------------------------------------------------
// Identity (verified): sigmoid(d)+sigmoid(-d)=1 makes A[b] = -0.5*theta, so
// out[b,n,:] = W_lin @ relu(-0.5*theta @ x[b,:,n]) + b_lin.
// Round 5: LOAD-DUTY-CYCLE fix.
//   r0-r2 post-mortem: per-CU outstanding bytes ~2KB (need ~10KB) -> loads in
//   flight only ~10% of the time. Register prefetch serialized (r2 VGPR=52:
//   compiler rematerialized weights + batched loads on vmcnt).
//   Fix: global_load_lds staging (zero VGPR, fire-and-forget, vmcnt-counted):
//   per tile, extract all frags from the wave-private slab (ds_read_b32),
//   lgkmcnt(0), then IMMEDIATELY re-issue 8 gload_lds into the same slab for
//   tile t+1; 32 MFMA + stores execute under the load latency. No barriers
//   anywhere (all LDS wave-private). Non-temporal out stores keep x L3-hot.
// mfma_f32_16x16x32_f16 layouts (HW-verified):
//   A[m=lane&15][k=quad*8+j]  B[col=lane&15][k=quad*8+j]  D[row=quad*4+r][col=lane&15]
// GEMM1 (swapped): D1 = M1 @ x   -> lane holds P[n=lq][i=4quad+r]
// GEMM2 (swapped): D2 = W  @ P^T -> lane holds out[n=lq][c=4quad+r] -> float4 NT stores
// LDS: xa linear [64ch][32px] f32 (gload_lds requires unpadded linear dest;
//   frag reads 4-way bank conflict = 1.58x on 32 b32/tile ~ negligible);
//   p2 stride 80 f16 (160B, 16B-aligned: b128 reads 2-way, b64 writes 4-way).
// ---------------------------------------------------------------------------

typedef _Float16 v8h __attribute__((ext_vector_type(8)));
typedef float    v4f __attribute__((ext_vector_type(4)));

union FragU { uint32_t u[4]; v8h h; };

__device__ inline uint32_t packf2(float lo, float hi) {
  union { _Float16 h[2]; uint32_t u; } r;
  r.h[0] = (_Float16)lo; r.h[1] = (_Float16)hi;
  return r.u;
}

__device__ inline v4f mfma16(v8h a, v8h b, v4f c) {
  return __builtin_amdgcn_mfma_f32_16x16x32_f16(a, b, c, 0, 0, 0);
}

__device__ inline void gload_lds16(const float* g, float* l) {
  __builtin_amdgcn_global_load_lds(
      (const __attribute__((address_space(1))) void*)g,
      (__attribute__((address_space(3))) void*)l, 16, 0, 0);
}

// Prep: f16 weights. M1h = -0.5*theta (row-major [i][c]); Wh = W_lin ([c][i]).
__global__ void prep_weights(const float* __restrict__ theta,
                             const float* __restrict__ Wlin,
                             _Float16* __restrict__ M1h,
                             _Float16* __restrict__ Wh) {
  int t = blockIdx.x * 256 + threadIdx.x;
  if (t < Cc * Cc) {
    M1h[t] = (_Float16)(-0.5f * theta[t]);
    Wh[t]  = (_Float16)(Wlin[t]);
  }
}

__global__ __launch_bounds__(256, 3) void fused_mfma(
    const float* __restrict__ x,      // [B, C, HW]
    const _Float16* __restrict__ M1h, // [64][64]
    const _Float16* __restrict__ Wh,  // [64][64]
    const float* __restrict__ blin,   // [64]
    float* __restrict__ out)          // [B, HW, C]
{
  // Wave-private: xa[wv] = x tile (f32, linear for gload_lds), p2[wv] = P scratch.
  __shared__ __align__(16) float    xa[4][64][32];   // 32768 B
  __shared__ __align__(16) _Float16 p2[4][32][80];   // 20480 B -> 3 blocks/CU

  const int tid  = threadIdx.x;
  const int wv   = tid >> 6;
  const int l    = tid & 63;
  const int lq   = tid & 15;
  const int quad = l >> 4;

  const int b     = blockIdx.x >> 5;                 // 32 blocks per batch
  const int npix0 = (blockIdx.x & 31) * 512 + wv * (TT * TPX);
  const float* xb = x + (size_t)b * Cc * HWc;

  // gload_lds lane mapping: instr i covers channels i*8+(l>>3), px (l&7)*4.
  // Dest is wave-uniform base; lane l writes 16B at base+l*16 -> [8ch][32px] f32.
  const int gch = l >> 3;
  const int gpx = (l & 7) * 4;

  // ---- weights + bias in registers (3 waves/EU -> 170 VGPR budget, no remat)
  const v8h* M1v = (const v8h*)M1h;
  const v8h* Whv = (const v8h*)Wh;
  v8h w1[4][2], w2[4][2];
#pragma unroll
  for (int it = 0; it < 4; ++it)
#pragma unroll
    for (int kt = 0; kt < 2; ++kt) {
      w1[it][kt] = M1v[(it * 16 + lq) * 8 + kt * 4 + quad];  // M1[i][c] A-frag
      w2[it][kt] = Whv[(it * 16 + lq) * 8 + kt * 4 + quad];  // W[c][i]  A-frag
    }
  v4f bias4[4];
#pragma unroll
  for (int ct = 0; ct < 4; ++ct)
    bias4[ct] = *(const v4f*)(blin + ct * 16 + quad * 4);

  // ---- prologue: stage tile 0 (8 x gload_lds, 1KB each, zero VGPR)
#pragma unroll
  for (int i = 0; i < 8; ++i)
    gload_lds16(xb + (size_t)(i * 8 + gch) * HWc + npix0 + gpx, &xa[wv][i * 8][0]);

#pragma unroll
  for (int t = 0; t < TT; ++t) {
    const int n0 = npix0 + t * TPX;

    // ---- extract ALL frag floats for this tile (compiler inserts vmcnt wait
    //      for the gload_lds that filled xa; reads are 4-way conflict = 1.58x)
    float f[2][2][4][2];
#pragma unroll
    for (int nt = 0; nt < 2; ++nt)
#pragma unroll
      for (int kt = 0; kt < 2; ++kt)
#pragma unroll
        for (int r = 0; r < 4; ++r) {
          const int c = kt * 16 + quad * 4 + r;
          f[nt][kt][r][0] = xa[wv][2 * c][nt * 16 + lq];
          f[nt][kt][r][1] = xa[wv][2 * c + 1][nt * 16 + lq];
        }
    // drain ds_reads so the slab is provably free, then re-issue immediately
    asm volatile("s_waitcnt lgkmcnt(0)" ::: "memory");
    __builtin_amdgcn_sched_barrier(0);

    // ---- prefetch tile t+1 into the SAME slab; latency hides under 32 MFMA
    if (t + 1 < TT) {
#pragma unroll
      for (int i = 0; i < 8; ++i)
        gload_lds16(xb + (size_t)(i * 8 + gch) * HWc + n0 + TPX + gpx,
                    &xa[wv][i * 8][0]);
    }

    // ---- compute both 16-px halves of the tile
#pragma unroll
    for (int nt = 0; nt < 2; ++nt) {
      FragU xf[2];
#pragma unroll
      for (int kt = 0; kt < 2; ++kt)
#pragma unroll
        for (int r = 0; r < 4; ++r)
          xf[kt].u[r] = packf2(f[nt][kt][r][0], f[nt][kt][r][1]);  // RTN f16 pair

      // GEMM1: D1[i][n] = M1 @ x ; relu+pack -> p2[n=lq][i] (b64 writes)
#pragma unroll
      for (int it = 0; it < 4; ++it) {
        v4f a = {0.f, 0.f, 0.f, 0.f};
        a = mfma16(w1[it][0], xf[0].h, a);
        a = mfma16(w1[it][1], xf[1].h, a);
        uint2 w;
        w.x = packf2(fmaxf(a[0], 0.f), fmaxf(a[1], 0.f));
        w.y = packf2(fmaxf(a[2], 0.f), fmaxf(a[3], 0.f));
        *(uint2*)&p2[wv][nt * 16 + lq][it * 16 + quad * 4] = w;
      }

      // P A-frags (in-wave lgkmcnt ordering; no barrier)
      FragU pr[2];
      pr[0].h = *(const v8h*)&p2[wv][nt * 16 + lq][quad * 8];
      pr[1].h = *(const v8h*)&p2[wv][nt * 16 + lq][32 + quad * 8];

      // GEMM2: D2[c][n] = W @ P^T -> out[n][c] float4 NON-TEMPORAL stores
      float* orow = out + ((size_t)b * HWc + n0 + nt * 16 + lq) * Cc + quad * 4;
#pragma unroll
      for (int ct = 0; ct < 4; ++ct) {
        v4f a = bias4[ct];
        a = mfma16(w2[ct][0], pr[0].h, a);
        a = mfma16(w2[ct][1], pr[1].h, a);
        __builtin_nontemporal_store(a, (v4f*)(orow + ct * 16));
      }
    }
  }
}

extern "C" void kernel_launch(void* const* d_in, const int* in_sizes, int n_in,
                              void* d_out, int out_size, void* d_ws, size_t ws_size,
                              hipStream_t stream) {
  const float* x     = (const float*)d_in[0];
  const float* theta = (const float*)d_in[1];
  const float* W_lin = (const float*)d_in[2];
  const float* b_lin = (const float*)d_in[3];
  float* out = (float*)d_out;

  _Float16* M1h = (_Float16*)d_ws;
  _Float16* Wh  = M1h + Cc * Cc;

  prep_weights<<<(Cc * Cc + 255) / 256, 256, 0, stream>>>(theta, W_lin, M1h, Wh);

  const int nblocks = Bc * HWc / 512;   // 1024 blocks; 3/CU resident, short tail
  fused_mfma<<<nblocks, 256, 0, stream>>>(x, M1h, Wh, b_lin, out);
}